// Round 4
// baseline (644.393 us; speedup 1.0000x reference)
//
#include <hip/hip_runtime.h>
#include <stdint.h>

typedef __attribute__((ext_vector_type(8))) short bf16x8;   // 8 bf16 = 4 VGPRs
typedef __attribute__((ext_vector_type(4))) float f32x4;
typedef unsigned short u16;

#define NUM_B 4
#define SEQ   2048
#define DM    1024
#define NH    16
#define DH    64
#define M_TOT (NUM_B * SEQ)   // 8192

__device__ __forceinline__ float bf2f(u16 u) {
    union { unsigned int i; float f; } c; c.i = ((unsigned int)u) << 16; return c.f;
}
__device__ __forceinline__ u16 f2bf(float f) {
    union { float f; unsigned int i; } c; c.f = f;
    unsigned int u = c.i;
    return (u16)((u + 0x7FFFu + ((u >> 16) & 1u)) >> 16);  // RNE
}
__device__ __forceinline__ unsigned int pack2(float a, float b) {
    return (unsigned int)f2bf(a) | ((unsigned int)f2bf(b) << 16);
}

// ---------------------------------------------------------------------------
// Input-dtype detector. bf16 N(0,1) values: exponent field in [110,145] for
// ~100% of entries. fp32 data viewed as u16 pairs: odd halves are valid
// truncated bf16 (~100% in range) but even halves are mantissa garbage
// (~14% in range) -> total ~57%. Threshold at 90%.
// flag: 0 = bf16 inputs, 1 = fp32 inputs.
// ---------------------------------------------------------------------------
__global__ void detect_dtype(const u16* __restrict__ x, int* __restrict__ flag) {
    __shared__ int cnt;
    if (threadIdx.x == 0) cnt = 0;
    __syncthreads();
    int local = 0;
    for (int i = threadIdx.x; i < 4096; i += 256) {
        const u16 v = x[i];
        const int e = (v >> 7) & 0xFF;
        if (v == 0 || (e >= 110 && e <= 145)) local++;
    }
    atomicAdd(&cnt, local);
    __syncthreads();
    if (threadIdx.x == 0) *flag = (cnt >= 3686) ? 0 : 1;
}

// ---------------------------------------------------------------------------
// GEMM: C[m,n] = sum_k A[m,k]*Bm[n,k] + bias[n]   (C = A @ Bm^T + bias)
// A_F32/B_F32: operand dtypes (fp32 converted to bf16 during LDS staging).
// OUT_F32: MODE-1 output dtype. bias dtype follows B_F32.
// MODE 0: scatter into Q/K/V [H][S][DH] chunks (bf16, workspace).
// MODE 1: plain store out0[m*N_TOT + n].
// Runs only when *mode_flag == my_mode (uniform early exit otherwise).
// 128x128 tile, BK=32, 256 threads (4 waves), wave = 64x64 via 4x4 MFMA.
// ---------------------------------------------------------------------------
template <int A_F32, int B_F32, int OUT_F32, int MODE, int N_TOT>
__global__ __launch_bounds__(256) void gemm_bt(
    const void* __restrict__ Av, const void* __restrict__ Bv,
    const void* __restrict__ biasv,
    void* __restrict__ out0v, u16* __restrict__ out1, u16* __restrict__ out2,
    const int* __restrict__ mode_flag, int my_mode,
    long a_off, long out_off)
{
    if (*mode_flag != my_mode) return;   // uniform across block

    __shared__ __align__(16) u16 As[128 * 32];
    __shared__ __align__(16) u16 Bs[128 * 32];
    const int K = 1024;

    const int tid  = threadIdx.x;
    const int wave = tid >> 6;
    const int lane = tid & 63;
    const int l15  = lane & 15;
    const int quad = lane >> 4;

    const int m0 = blockIdx.y * 128;
    const int n0 = blockIdx.x * 128;
    const int wm = (wave >> 1) * 64;
    const int wn = (wave & 1) * 64;

    f32x4 acc[4][4];
#pragma unroll
    for (int i = 0; i < 4; ++i)
#pragma unroll
        for (int j = 0; j < 4; ++j)
            acc[i][j] = (f32x4){0.f, 0.f, 0.f, 0.f};

    for (int k0 = 0; k0 < K; k0 += 32) {
        // ---- stage A tile ----
        if (!A_F32) {
            const u16* A = (const u16*)Av + a_off;
#pragma unroll
            for (int r = 0; r < 2; ++r) {
                int c   = tid + r * 256;
                int row = c >> 2;
                int off = (c & 3) * 8;
                *(uint4*)(&As[row * 32 + off]) =
                    *(const uint4*)(&A[(size_t)(m0 + row) * K + k0 + off]);
            }
        } else {
            const float* A = (const float*)Av + a_off;
#pragma unroll
            for (int r = 0; r < 4; ++r) {
                int c   = tid + r * 256;
                int row = c >> 3;
                int off = (c & 7) * 4;
                float4 f = *(const float4*)(&A[(size_t)(m0 + row) * K + k0 + off]);
                uint2 p; p.x = pack2(f.x, f.y); p.y = pack2(f.z, f.w);
                *(uint2*)(&As[row * 32 + off]) = p;
            }
        }
        // ---- stage B tile ----
        if (!B_F32) {
            const u16* Bm = (const u16*)Bv;
#pragma unroll
            for (int r = 0; r < 2; ++r) {
                int c   = tid + r * 256;
                int row = c >> 2;
                int off = (c & 3) * 8;
                *(uint4*)(&Bs[row * 32 + off]) =
                    *(const uint4*)(&Bm[(size_t)(n0 + row) * K + k0 + off]);
            }
        } else {
            const float* Bm = (const float*)Bv;
#pragma unroll
            for (int r = 0; r < 4; ++r) {
                int c   = tid + r * 256;
                int row = c >> 3;
                int off = (c & 7) * 4;
                float4 f = *(const float4*)(&Bm[(size_t)(n0 + row) * K + k0 + off]);
                uint2 p; p.x = pack2(f.x, f.y); p.y = pack2(f.z, f.w);
                *(uint2*)(&Bs[row * 32 + off]) = p;
            }
        }
        __syncthreads();

        bf16x8 af[4], bfv[4];
#pragma unroll
        for (int i = 0; i < 4; ++i)
            af[i] = *(const bf16x8*)(&As[(wm + i * 16 + l15) * 32 + quad * 8]);
#pragma unroll
        for (int j = 0; j < 4; ++j)
            bfv[j] = *(const bf16x8*)(&Bs[(wn + j * 16 + l15) * 32 + quad * 8]);

#pragma unroll
        for (int i = 0; i < 4; ++i)
#pragma unroll
            for (int j = 0; j < 4; ++j)
                acc[i][j] = __builtin_amdgcn_mfma_f32_16x16x32_bf16(
                    af[i], bfv[j], acc[i][j], 0, 0, 0);
        __syncthreads();
    }

    // epilogue: D[row][col], col = lane&15, row = quad*4 + reg  [m89-verified]
#pragma unroll
    for (int j = 0; j < 4; ++j) {
        const int n  = n0 + wn + j * 16 + l15;
        const float bv = B_F32 ? ((const float*)biasv)[n]
                               : bf2f(((const u16*)biasv)[n]);
#pragma unroll
        for (int i = 0; i < 4; ++i) {
#pragma unroll
            for (int reg = 0; reg < 4; ++reg) {
                const int m = m0 + wm + i * 16 + quad * 4 + reg;
                const float v = acc[i][j][reg] + bv;
                if (MODE == 0) {
                    const int sel = n >> 10;         // 0=Q 1=K 2=V
                    const int h   = (n >> 6) & 15;
                    const int dh  = n & 63;
                    const int b   = m >> 11;         // 0 in per-batch mode
                    const int s   = m & 2047;
                    u16* dst = (sel == 0) ? (u16*)out0v : ((sel == 1) ? out1 : out2);
                    dst[((size_t)((b * NH + h) * SEQ + s)) * DH + dh] = f2bf(v);
                } else {
                    if (OUT_F32)
                        ((float*)out0v)[out_off + (size_t)m * N_TOT + n] = v;
                    else
                        ((u16*)out0v)[out_off + (size_t)m * N_TOT + n] = f2bf(v);
                }
            }
        }
    }
}

// ---------------------------------------------------------------------------
// Flash attention, causal. Q/K/V: [H_chunk, S, DH] bf16 (workspace, both
// modes). ctx out: bf16 [rows, DM]. Block = 4 waves; wave w owns q rows
// [blockIdx.x*64 + w*16, +16). K-tile = 32. Block-uniform trip count so
// __syncthreads() legally guards the P C-layout->A-layout LDS round-trip;
// extra tiles for early waves are fully masked (p=0, alpha=1 -> inert).
// ---------------------------------------------------------------------------
__global__ __launch_bounds__(256) void attn_fwd(
    const u16* __restrict__ Qb, const u16* __restrict__ Kb,
    const u16* __restrict__ Vb, u16* __restrict__ ctx)
{
    __shared__ __align__(16) short Pbuf[4][16 * 32];   // per-wave region

    const int tid  = threadIdx.x;
    const int wave = tid >> 6;
    const int lane = tid & 63;
    const int l15  = lane & 15;
    const int quad = lane >> 4;

    const int bh = blockIdx.y;
    const int q0 = blockIdx.x * 64 + wave * 16;
    const size_t base = (size_t)bh * SEQ * DH;
    const float scale = 0.125f;                 // 1/sqrt(64)

    bf16x8 qf[2];
#pragma unroll
    for (int c = 0; c < 2; ++c)
        qf[c] = *(const bf16x8*)(&Qb[base + (size_t)(q0 + l15) * DH + c * 32 + quad * 8]);

    f32x4 acc[4];
#pragma unroll
    for (int j = 0; j < 4; ++j) acc[j] = (f32x4){0.f, 0.f, 0.f, 0.f};
    float mst[4], lst[4];
#pragma unroll
    for (int r = 0; r < 4; ++r) { mst[r] = -1e30f; lst[r] = 0.f; }

    const int ktmax = (blockIdx.x * 64 + 63) >> 5;   // block-uniform
    for (int kt = 0; kt <= ktmax; ++kt) {
        const int k0 = kt * 32;

        bf16x8 kf0[2], kf1[2];
#pragma unroll
        for (int c = 0; c < 2; ++c) {
            kf0[c] = *(const bf16x8*)(&Kb[base + (size_t)(k0 + l15) * DH + c * 32 + quad * 8]);
            kf1[c] = *(const bf16x8*)(&Kb[base + (size_t)(k0 + 16 + l15) * DH + c * 32 + quad * 8]);
        }

        f32x4 scA = (f32x4){0.f, 0.f, 0.f, 0.f};
        f32x4 scB = (f32x4){0.f, 0.f, 0.f, 0.f};
        scA = __builtin_amdgcn_mfma_f32_16x16x32_bf16(qf[0], kf0[0], scA, 0, 0, 0);
        scA = __builtin_amdgcn_mfma_f32_16x16x32_bf16(qf[1], kf0[1], scA, 0, 0, 0);
        scB = __builtin_amdgcn_mfma_f32_16x16x32_bf16(qf[0], kf1[0], scB, 0, 0, 0);
        scB = __builtin_amdgcn_mfma_f32_16x16x32_bf16(qf[1], kf1[1], scB, 0, 0, 0);

        const int colA = k0 + l15;
        const int colB = k0 + 16 + l15;
        float sa[4], sb[4], tmax[4];
#pragma unroll
        for (int r = 0; r < 4; ++r) {
            const int qrow = q0 + quad * 4 + r;
            sa[r] = (colA <= qrow) ? scA[r] * scale : -1e30f;
            sb[r] = (colB <= qrow) ? scB[r] * scale : -1e30f;
            tmax[r] = fmaxf(sa[r], sb[r]);
        }
#pragma unroll
        for (int off = 1; off <= 8; off <<= 1)
#pragma unroll
            for (int r = 0; r < 4; ++r)
                tmax[r] = fmaxf(tmax[r], __shfl_xor(tmax[r], off));

        float pa[4], pb[4], tsum[4], alpha[4];
#pragma unroll
        for (int r = 0; r < 4; ++r) {
            const float mn = fmaxf(mst[r], tmax[r]);
            alpha[r] = __expf(mst[r] - mn);
            pa[r] = __expf(sa[r] - mn);
            pb[r] = __expf(sb[r] - mn);
            mst[r] = mn;
            tsum[r] = pa[r] + pb[r];
        }
#pragma unroll
        for (int off = 1; off <= 8; off <<= 1)
#pragma unroll
            for (int r = 0; r < 4; ++r)
                tsum[r] += __shfl_xor(tsum[r], off);
#pragma unroll
        for (int r = 0; r < 4; ++r)
            lst[r] = lst[r] * alpha[r] + tsum[r];

#pragma unroll
        for (int j = 0; j < 4; ++j)
#pragma unroll
            for (int r = 0; r < 4; ++r)
                acc[j][r] *= alpha[r];

        __syncthreads();
        short* pw = Pbuf[wave];
#pragma unroll
        for (int r = 0; r < 4; ++r) {
            const int row = quad * 4 + r;
            pw[row * 32 + l15]      = (short)f2bf(pa[r]);
            pw[row * 32 + 16 + l15] = (short)f2bf(pb[r]);
        }
        __syncthreads();
        const bf16x8 pf = *(const bf16x8*)(&pw[l15 * 32 + quad * 8]);

#pragma unroll
        for (int j = 0; j < 4; ++j) {
            bf16x8 vf;
#pragma unroll
            for (int j2 = 0; j2 < 8; ++j2)
                vf[j2] = (short)Vb[base + (size_t)(k0 + quad * 8 + j2) * DH + j * 16 + l15];
            acc[j] = __builtin_amdgcn_mfma_f32_16x16x32_bf16(pf, vf, acc[j], 0, 0, 0);
        }
    }

    const int b = bh >> 4;        // 0 in per-batch mode (gridDim.y == 16)
    const int h = bh & 15;
#pragma unroll
    for (int j = 0; j < 4; ++j) {
#pragma unroll
        for (int r = 0; r < 4; ++r) {
            const int qrow = q0 + quad * 4 + r;
            const float v = acc[j][r] / lst[r];
            ctx[(size_t)(b * SEQ + qrow) * DM + h * DH + j * 16 + l15] = f2bf(v);
        }
    }
}

// ---------------------------------------------------------------------------
extern "C" void kernel_launch(void* const* d_in, const int* in_sizes, int n_in,
                              void* d_out, int out_size, void* d_ws, size_t ws_size,
                              hipStream_t stream)
{
    // Locate tensors by element count (immune to ordering / mask omission).
    auto find = [&](long want, int fb) -> const void* {
        for (int i = 0; i < n_in; ++i)
            if ((long)in_sizes[i] == want) return d_in[i];
        if (fb >= n_in) fb = n_in - 1;
        return d_in[fb];
    };
    const void* x     = find(8388608, 0);   // [4,2048,1024]
    const void* w_qkv = find(3145728, 2);   // [3072,1024]
    const void* b_qkv = find(3072,    3);   // [3072]
    const void* w_out = find(1048576, 4);   // [1024,1024]
    const void* b_out = find(1024,    5);   // [1024]

    char* ws   = (char*)d_ws;
    int*  flag = (int*)ws;
    char* pool = ws + 256;

    const size_t tensor_bytes = (size_t)M_TOT * DM * sizeof(u16);     // 16.78 MB
    const size_t chunk_bytes  = tensor_bytes / NUM_B;                 // 4.19 MB

    detect_dtype<<<1, 256, 0, stream>>>((const u16*)x, flag);

    if (ws_size >= 4 * tensor_bytes + 256) {
        u16* Qb  = (u16*)(pool);
        u16* Kb  = (u16*)(pool + tensor_bytes);
        u16* Vb  = (u16*)(pool + 2 * tensor_bytes);
        u16* ctx = (u16*)(pool + 3 * tensor_bytes);

        gemm_bt<0,0,0,0,3072><<<dim3(24, 64), 256, 0, stream>>>(
            x, w_qkv, b_qkv, Qb, Kb, Vb, flag, 0, 0, 0);
        gemm_bt<1,1,0,0,3072><<<dim3(24, 64), 256, 0, stream>>>(
            x, w_qkv, b_qkv, Qb, Kb, Vb, flag, 1, 0, 0);
        attn_fwd<<<dim3(32, NUM_B * NH), 256, 0, stream>>>(Qb, Kb, Vb, ctx);
        gemm_bt<0,0,0,1,1024><<<dim3(8, 64), 256, 0, stream>>>(
            ctx, w_out, b_out, d_out, nullptr, nullptr, flag, 0, 0, 0);
        gemm_bt<0,1,1,1,1024><<<dim3(8, 64), 256, 0, stream>>>(
            ctx, w_out, b_out, d_out, nullptr, nullptr, flag, 1, 0, 0);
    } else {
        // per-batch pipeline: 256 B flag + 4 chunks = ~17 MB
        u16* Qb  = (u16*)(pool);
        u16* Kb  = (u16*)(pool + chunk_bytes);
        u16* Vb  = (u16*)(pool + 2 * chunk_bytes);
        u16* ctx = (u16*)(pool + 3 * chunk_bytes);
        for (int b = 0; b < NUM_B; ++b) {
            const long eoff = (long)b * SEQ * DM;   // element offset
            gemm_bt<0,0,0,0,3072><<<dim3(24, 16), 256, 0, stream>>>(
                x, w_qkv, b_qkv, Qb, Kb, Vb, flag, 0, eoff, 0);
            gemm_bt<1,1,0,0,3072><<<dim3(24, 16), 256, 0, stream>>>(
                x, w_qkv, b_qkv, Qb, Kb, Vb, flag, 1, eoff, 0);
            attn_fwd<<<dim3(32, NH), 256, 0, stream>>>(Qb, Kb, Vb, ctx);
            gemm_bt<0,0,0,1,1024><<<dim3(8, 16), 256, 0, stream>>>(
                ctx, w_out, b_out, d_out, nullptr, nullptr, flag, 0, 0, eoff);
            gemm_bt<0,1,1,1,1024><<<dim3(8, 16), 256, 0, stream>>>(
                ctx, w_out, b_out, d_out, nullptr, nullptr, flag, 1, 0, eoff);
        }
    }
}